// Round 4
// baseline (150.729 us; speedup 1.0000x reference)
//
#include <hip/hip_runtime.h>

#define HH 512
#define WW 512
#define PD 544                          // 512 + 2*16
#define PADN (3 * PD * PD)              // 887808 bf16 elements
#define OUTN (3 * HH * WW)
#define NB 128
#define KSTR 16384                      // 128*128 floats between taps

// ---------------- pad + out-zero: fp32 img -> bf16 edge-padded ----------------
__global__ __launch_bounds__(256) void pad_kernel(const float* __restrict__ img,
                                                  unsigned short* __restrict__ gpad,
                                                  float* __restrict__ out) {
    int idx = blockIdx.x * 256 + threadIdx.x;
    if (idx < OUTN) out[idx] = 0.0f;           // zero the atomic target
    if (idx >= PADN) return;
    int c  = idx / (PD * PD);
    int r  = idx - c * (PD * PD);
    int py = r / PD;
    int px = r - py * PD;
    int iy = min(max(py - 16, 0), HH - 1);
    int ix = min(max(px - 16, 0), WW - 1);
    union { float f; unsigned u; } v;
    v.f = img[(c * HH + iy) * WW + ix];
    unsigned u = v.u + 0x7FFFu + ((v.u >> 16) & 1u);   // RNE bf16
    gpad[idx] = (unsigned short)(u >> 16);
}

// ---- async global->LDS (wave-uniform LDS base; HW puts lane i at base+i*size) ----
__device__ __forceinline__ void async16u(const unsigned short* g, unsigned short* l) {
    __builtin_amdgcn_global_load_lds((const __attribute__((address_space(1))) void*)g,
                                     (__attribute__((address_space(3))) void*)l, 16, 0, 0);
}
__device__ __forceinline__ float bflo(unsigned d) { union { unsigned u; float f; } x; x.u = d << 16;         return x.f; }
__device__ __forceinline__ float bfhi(unsigned d) { union { unsigned u; float f; } x; x.u = d & 0xFFFF0000u; return x.f; }

// ---------------- main kernel ----------------
// ROUND 10: BARRIER-FREE. ROUND-9 LESSON: occupancy 17.8->27.7% changed
// nothing (66us, VALUBusy 41% in both round 0 and round 3) because the per-
// iteration s_barrier keeps the 4 waves of a block PHASE-LOCKED: all arrive
// together, all issue 33 weight loads together, all co-stall on the same
// L2 dependency. Extra waves can't hide latency they all incur simultaneously.
//
// Fix: each wave gets a PRIVATE 4-slot LDS row ring (wave dy stages its own
// rows y+ua+t; [dy][slot][c][288] = 27.6 KB total). No s_barrier at all.
// Per-wave sync only:
//   - lgkmcnt(0) before staging (ring slot reuse guard; free in steady state)
//   - vmcnt(3) after staging (allow only the 3 just-issued stage ops to be
//     outstanding -> everything older incl. stage(t) has landed; stage(t)
//     was issued 3 iterations ago so this passes instantly in steady state)
//   - sched_barrier(0) pins ds_reads below the vmcnt (rule: compiler may
//     hoist otherwise)
// Waves now slip phase freely: one wave's FMA phase hides another's weight
// latency. Cost: 4x image stage traffic from L2 (58 vs 19 MB, trivial).
//
// Rest as round 9: 4 u-chunks (9+8+8+8) x 128 h x 2 wt = 1024 blocks of 256
// thr; weights single-buffered global->reg per iter (L2/L3-resident); window
// read = 9 ds_read_b64/channel; u-chunks combine via atomicAdd into the
// pad_kernel-zeroed out. __launch_bounds__(256,2): this toolchain caps VGPR
// at 256/minwaves ((256,4) forced 64-cap + spills in round 7; (256,2) gave a
// clean 64-VGPR build in round 9).
__global__ __launch_bounds__(256, 2) void reblur_kernel(const unsigned short* __restrict__ gpad,
                                                        const float* __restrict__ Kern,
                                                        float* __restrict__ out) {
    __shared__ unsigned short s_img[4][4][3][288];   // [dy][slot][c][288] = 27648 B

    const int lane = threadIdx.x & 63;
    const int dy   = threadIdx.x >> 6;            // wave id 0..3
    const int uq   = blockIdx.x >> 8;             // u-chunk 0..3
    const int bb   = blockIdx.x & 255;
    const int h    = bb >> 1;                     // 0..127
    const int wt   = bb & 1;                      // 0..1
    const int ua   = uq ? (8 * uq + 1) : 0;       // chunk start u: 0,9,17,25
    const int n    = uq ? 8 : 9;                  // chunk length (sums to 33)
    const int kofs = h * NB + wt * 64 + lane;     // per-lane weight dword offset
    const int y    = 4 * h + dy;                  // this wave's output row

    // ---- prologue: stage this wave's image rows for iters 0,1,2 (slots 0,1,2) ----
    if (lane < 36) {
#pragma unroll
        for (int p = 0; p < 3; ++p)
#pragma unroll
            for (int c = 0; c < 3; ++c)
                async16u(gpad + ((size_t)(c * PD + y + ua + p) * PD + 256 * wt) + 8 * lane,
                         &s_img[dy][p][c][0]);
    }

    float acc[3][4];
#pragma unroll
    for (int c = 0; c < 3; ++c)
#pragma unroll
        for (int oj = 0; oj < 4; ++oj) acc[c][oj] = 0.0f;

#pragma unroll 1
    for (int t = 0; t < n; ++t) {
        // ring-slot reuse guard: our own ds_reads of slot (t-1)&3 must have
        // retired before stage(t+3) can overwrite it (free in steady state)
        asm volatile("s_waitcnt lgkmcnt(0)" ::: "memory");

        // stage image row for iteration t+3 into private ring slot (t+3)&3
        if (t + 3 < n && lane < 36) {
            const int r = y + ua + t + 3;
#pragma unroll
            for (int c = 0; c < 3; ++c)
                async16u(gpad + ((size_t)(c * PD + r) * PD + 256 * wt) + 8 * lane,
                         &s_img[dy][(t + 3) & 3][c][0]);
        }

        // stage(t) (issued 3 iters ago) must have landed before the ds_reads
        // below; allow only the 3 just-issued stage ops to remain in flight
        asm volatile("s_waitcnt vmcnt(3)" ::: "memory");
        __builtin_amdgcn_sched_barrier(0);

        // weights for u = ua+t, single-buffered; L2/L3-resident, latency
        // hidden by the other phase-slipped waves on this SIMD
        float wA[33];
#pragma unroll
        for (int v = 0; v < 33; ++v)
            wA[v] = Kern[(size_t)((ua + t) * 33 + v) * KSTR + kofs];

        const int slot = t & 3;
#pragma unroll
        for (int c = 0; c < 3; ++c) {
            float wf[36];
            const unsigned short* sp = &s_img[dy][slot][c][4 * lane];
#pragma unroll
            for (int j = 0; j < 9; ++j) {
                const uint2 dd = *(const uint2*)(sp + 4 * j);
                wf[4 * j + 0] = bflo(dd.x);
                wf[4 * j + 1] = bfhi(dd.x);
                wf[4 * j + 2] = bflo(dd.y);
                wf[4 * j + 3] = bfhi(dd.y);
            }
#pragma unroll
            for (int v = 0; v < 33; ++v) {
#pragma unroll
                for (int oj = 0; oj < 4; ++oj)
                    acc[c][oj] = fmaf(wf[v + oj], wA[v], acc[c][oj]);
            }
        }
    }

    // ---- epilogue: 4 u-chunks accumulate into the pad_kernel-zeroed output ----
    const int xb = 4 * (wt * 64 + lane);
#pragma unroll
    for (int c = 0; c < 3; ++c) {
        float* op = out + (size_t)(c * HH + y) * WW + xb;
#pragma unroll
        for (int oj = 0; oj < 4; ++oj) atomicAdd(op + oj, acc[c][oj]);
    }
}

// ---------------- fallback (ws too small): naive but correct ----------------
__global__ __launch_bounds__(256) void reblur_naive(const float* __restrict__ img,
                                                    const float* __restrict__ Kern,
                                                    float* __restrict__ out) {
    const int lane = threadIdx.x & 63;
    const int dy   = threadIdx.x >> 6;
    const int c    = blockIdx.x >> 8;
    const int bb   = blockIdx.x & 255;
    const int h    = bb >> 1;
    const int wt   = bb & 1;
    const int wb   = wt * 64 + lane;
    const int y    = 4 * h + dy;

    float acc[4] = {0.f, 0.f, 0.f, 0.f};
    const float* kb = Kern + h * NB + wb;
#pragma unroll 1
    for (int u = 0; u < 33; ++u) {
        const int iy = min(max(y + u - 16, 0), HH - 1);
        float row[36];
#pragma unroll
        for (int e = 0; e < 36; ++e) {
            const int ix = min(max(4 * wb + e - 16, 0), WW - 1);
            row[e]       = img[(c * HH + iy) * WW + ix];
        }
#pragma unroll
        for (int v = 0; v < 33; ++v) {
            const float w = kb[(u * 33 + v) * KSTR];
#pragma unroll
            for (int oj = 0; oj < 4; ++oj)
                acc[oj] = fmaf(row[v + oj], w, acc[oj]);
        }
    }
    float4 o;
    o.x = acc[0]; o.y = acc[1]; o.z = acc[2]; o.w = acc[3];
    *reinterpret_cast<float4*>(out + (size_t)(c * HH + y) * WW + 4 * wb) = o;
}

extern "C" void kernel_launch(void* const* d_in, const int* in_sizes, int n_in,
                              void* d_out, int out_size, void* d_ws, size_t ws_size,
                              hipStream_t stream) {
    const float* img  = (const float*)d_in[0];
    const float* Kern = (const float*)d_in[1];
    float* out        = (float*)d_out;

    if (ws_size >= (size_t)PADN * sizeof(unsigned short)) {
        unsigned short* gpad = (unsigned short*)d_ws;
        pad_kernel<<<(PADN + 255) / 256, 256, 0, stream>>>(img, gpad, out);
        reblur_kernel<<<1024, 256, 0, stream>>>(gpad, Kern, out);
    } else {
        reblur_naive<<<768, 256, 0, stream>>>(img, Kern, out);
    }
}

// Round 5
// 148.540 us; speedup vs baseline: 1.0147x; 1.0147x over previous
//
#include <hip/hip_runtime.h>

#define HH 512
#define WW 512
#define PD 544                          // 512 + 2*16
#define PADN (3 * PD * PD)              // padded elements per 3 channels
#define OUTN (3 * HH * WW)
#define NB 128
#define KSTR 16384                      // 128*128 floats between taps

typedef float f2 __attribute__((ext_vector_type(2)));

// ---------------- pad + out-zero: fp32 img -> fp32 edge-padded ----------------
__global__ __launch_bounds__(256) void pad_f32(const float* __restrict__ img,
                                               float* __restrict__ gpad,
                                               float* __restrict__ out) {
    int idx = blockIdx.x * 256 + threadIdx.x;
    if (idx < OUTN) out[idx] = 0.0f;           // zero the atomic target
    if (idx >= PADN) return;
    int c  = idx / (PD * PD);
    int r  = idx - c * (PD * PD);
    int py = r / PD;
    int px = r - py * PD;
    int iy = min(max(py - 16, 0), HH - 1);
    int ix = min(max(px - 16, 0), WW - 1);
    gpad[idx] = img[(c * HH + iy) * WW + ix];
}

// ---------------- pad + out-zero: fp32 img -> bf16 edge-padded (fallback) -----
__global__ __launch_bounds__(256) void pad_bf16(const float* __restrict__ img,
                                                unsigned short* __restrict__ gpad,
                                                float* __restrict__ out) {
    int idx = blockIdx.x * 256 + threadIdx.x;
    if (idx < OUTN) out[idx] = 0.0f;
    if (idx >= PADN) return;
    int c  = idx / (PD * PD);
    int r  = idx - c * (PD * PD);
    int py = r / PD;
    int px = r - py * PD;
    int iy = min(max(py - 16, 0), HH - 1);
    int ix = min(max(px - 16, 0), WW - 1);
    union { float f; unsigned u; } v;
    v.f = img[(c * HH + iy) * WW + ix];
    unsigned u = v.u + 0x7FFFu + ((v.u >> 16) & 1u);   // RNE bf16
    gpad[idx] = (unsigned short)(u >> 16);
}

// ---- async global->LDS (wave-uniform LDS base; HW puts lane i at base+i*size) ----
__device__ __forceinline__ void async16f(const float* g, float* l) {
    __builtin_amdgcn_global_load_lds((const __attribute__((address_space(1))) void*)g,
                                     (__attribute__((address_space(3))) void*)l, 16, 0, 0);
}
__device__ __forceinline__ void async16u(const unsigned short* g, unsigned short* l) {
    __builtin_amdgcn_global_load_lds((const __attribute__((address_space(1))) void*)g,
                                     (__attribute__((address_space(3))) void*)l, 16, 0, 0);
}
__device__ __forceinline__ float bflo(unsigned d) { union { unsigned u; float f; } x; x.u = d << 16;         return x.f; }
__device__ __forceinline__ float bfhi(unsigned d) { union { unsigned u; float f; } x; x.u = d & 0xFFFF0000u; return x.f; }

// ---------------- main kernel (fp32 image path) ----------------
// ROUND 11: SHRINK THE INSTRUCTION STREAM. Rounds 0-4 falsified the latency
// program: barrier vs no-barrier, 2 vs 4 blocks/CU, weight dbuf vs single --
// all tie at 64-67us, VALUBusy ~41%. The wall is per-wave issue work, not
// hidable latency. Two cuts, stacked:
//  1) fp32 image in LDS: ds_read_b128 delivers ready floats -> the 108
//     bf16-unpack VALU ops per wave-iter vanish (also removes bf16 rounding;
//     absmax should drop 1.0 -> ~1e-3).
//  2) packed fp32 FMA: CDNA4's 157 TF fp32 peak is the PACKED (v_pk_fma_f32)
//     rate; scalar v_fma is half. Accumulators reformulated as float2
//     (aL = oj0,1 / aH = oj2,3) with splat weights -- the SLP-friendly shape
//     for the backend to emit VOP3P pk_fma, halving FMA issue 396 -> ~198.
// Structure: shared 8-slot fp32 ring (27.6 KB), per-iter vmcnt(0)+s_barrier
// (proved cost-equal to barrier-free, half the LDS). 4 u-chunks (9+8+8+8) x
// 128 h x 2 wt = 1024 blocks of 256 thr. Weights single-buffered global->reg.
// Row stage = 2 global_load_lds per channel (288 floats = 64x16B + 8x16B).
__global__ __launch_bounds__(256, 2) void reblur_f32(const float* __restrict__ gpad,
                                                     const float* __restrict__ Kern,
                                                     float* __restrict__ out) {
    __shared__ float s_img[8][3][288];            // 27648 B, ring over padded rows

    const int lane = threadIdx.x & 63;
    const int dy   = threadIdx.x >> 6;            // wave id 0..3
    const int uq   = blockIdx.x >> 8;             // u-chunk 0..3
    const int bb   = blockIdx.x & 255;
    const int h    = bb >> 1;                     // 0..127
    const int wt   = bb & 1;                      // 0..1
    const int ua   = uq ? (8 * uq + 1) : 0;       // chunk start u: 0,9,17,25
    const int n    = uq ? 8 : 9;                  // chunk length (sums to 33)
    const int kofs = h * NB + wt * 64 + lane;     // per-lane weight dword offset

    // ---- prologue: wave dy stages padded row 4h+ua+dy (x3 channels) ----
    {
        const int r = 4 * h + ua + dy;
#pragma unroll
        for (int c = 0; c < 3; ++c) {
            const float* gp = gpad + (size_t)(c * PD + r) * PD + 256 * wt;
            async16f(gp + 4 * lane, &s_img[r & 7][c][0]);
            if (lane < 8)
                async16f(gp + 256 + 4 * lane, &s_img[r & 7][c][256]);
        }
    }

    f2 accL[3], accH[3];                          // (oj0,oj1) and (oj2,oj3)
#pragma unroll
    for (int c = 0; c < 3; ++c) { accL[c] = (f2)(0.0f); accH[c] = (f2)(0.0f); }

#pragma unroll 1
    for (int t = 0; t < n; ++t) {
        // all prior global_load_lds (image rows) have landed; sync the ring
        asm volatile("s_waitcnt vmcnt(0)" ::: "memory");
        __builtin_amdgcn_s_barrier();

        // weights for u = ua+t; L2/L3-resident, latency hidden under the
        // ds_read phase below
        float wA[33];
#pragma unroll
        for (int v = 0; v < 33; ++v)
            wA[v] = Kern[(size_t)((ua + t) * 33 + v) * KSTR + kofs];

        // stage padded row for iteration t+1 (row 4h+ua+t+4)
        if (t + 1 < n && dy == (t & 3)) {
            const int r = 4 * h + ua + t + 4;
#pragma unroll
            for (int c = 0; c < 3; ++c) {
                const float* gp = gpad + (size_t)(c * PD + r) * PD + 256 * wt;
                async16f(gp + 4 * lane, &s_img[r & 7][c][0]);
                if (lane < 8)
                    async16f(gp + 256 + 4 * lane, &s_img[r & 7][c][256]);
            }
        }

        const int slot = (4 * h + ua + t + dy) & 7;
#pragma unroll
        for (int c = 0; c < 3; ++c) {
            float wf[36];
            const float4* sp = (const float4*)&s_img[slot][c][4 * lane];
#pragma unroll
            for (int j = 0; j < 9; ++j) {
                const float4 rr = sp[j];           // ds_read_b128, no unpack
                wf[4 * j + 0] = rr.x;
                wf[4 * j + 1] = rr.y;
                wf[4 * j + 2] = rr.z;
                wf[4 * j + 3] = rr.w;
            }
            f2 aL = accL[c], aH = accH[c];
#pragma unroll
            for (int v = 0; v < 33; ++v) {
                const f2 w2 = {wA[v], wA[v]};
                const f2 xl = {wf[v + 0], wf[v + 1]};
                const f2 xh = {wf[v + 2], wf[v + 3]};
                aL = xl * w2 + aL;                 // -> v_pk_fma_f32
                aH = xh * w2 + aH;
            }
            accL[c] = aL; accH[c] = aH;
        }
    }

    // ---- epilogue: 4 u-chunks accumulate into the pad-zeroed output ----
    const int xb = 4 * (wt * 64 + lane);
#pragma unroll
    for (int c = 0; c < 3; ++c) {
        float* op = out + (size_t)(c * HH + 4 * h + dy) * WW + xb;
        atomicAdd(op + 0, accL[c].x);
        atomicAdd(op + 1, accL[c].y);
        atomicAdd(op + 2, accH[c].x);
        atomicAdd(op + 3, accH[c].y);
    }
}

// ---------------- bf16 fallback kernel (round-4 structure, proven) ----------
__global__ __launch_bounds__(256, 2) void reblur_bf16(const unsigned short* __restrict__ gpad,
                                                      const float* __restrict__ Kern,
                                                      float* __restrict__ out) {
    __shared__ unsigned short s_img[4][4][3][288];

    const int lane = threadIdx.x & 63;
    const int dy   = threadIdx.x >> 6;
    const int uq   = blockIdx.x >> 8;
    const int bb   = blockIdx.x & 255;
    const int h    = bb >> 1;
    const int wt   = bb & 1;
    const int ua   = uq ? (8 * uq + 1) : 0;
    const int n    = uq ? 8 : 9;
    const int kofs = h * NB + wt * 64 + lane;
    const int y    = 4 * h + dy;

    if (lane < 36) {
#pragma unroll
        for (int p = 0; p < 3; ++p)
#pragma unroll
            for (int c = 0; c < 3; ++c)
                async16u(gpad + ((size_t)(c * PD + y + ua + p) * PD + 256 * wt) + 8 * lane,
                         &s_img[dy][p][c][0]);
    }

    float acc[3][4];
#pragma unroll
    for (int c = 0; c < 3; ++c)
#pragma unroll
        for (int oj = 0; oj < 4; ++oj) acc[c][oj] = 0.0f;

#pragma unroll 1
    for (int t = 0; t < n; ++t) {
        asm volatile("s_waitcnt lgkmcnt(0)" ::: "memory");
        if (t + 3 < n && lane < 36) {
            const int r = y + ua + t + 3;
#pragma unroll
            for (int c = 0; c < 3; ++c)
                async16u(gpad + ((size_t)(c * PD + r) * PD + 256 * wt) + 8 * lane,
                         &s_img[dy][(t + 3) & 3][c][0]);
        }
        asm volatile("s_waitcnt vmcnt(3)" ::: "memory");
        __builtin_amdgcn_sched_barrier(0);

        float wA[33];
#pragma unroll
        for (int v = 0; v < 33; ++v)
            wA[v] = Kern[(size_t)((ua + t) * 33 + v) * KSTR + kofs];

        const int slot = t & 3;
#pragma unroll
        for (int c = 0; c < 3; ++c) {
            float wf[36];
            const unsigned short* sp = &s_img[dy][slot][c][4 * lane];
#pragma unroll
            for (int j = 0; j < 9; ++j) {
                const uint2 dd = *(const uint2*)(sp + 4 * j);
                wf[4 * j + 0] = bflo(dd.x);
                wf[4 * j + 1] = bfhi(dd.x);
                wf[4 * j + 2] = bflo(dd.y);
                wf[4 * j + 3] = bfhi(dd.y);
            }
#pragma unroll
            for (int v = 0; v < 33; ++v) {
#pragma unroll
                for (int oj = 0; oj < 4; ++oj)
                    acc[c][oj] = fmaf(wf[v + oj], wA[v], acc[c][oj]);
            }
        }
    }

    const int xb = 4 * (wt * 64 + lane);
#pragma unroll
    for (int c = 0; c < 3; ++c) {
        float* op = out + (size_t)(c * HH + y) * WW + xb;
#pragma unroll
        for (int oj = 0; oj < 4; ++oj) atomicAdd(op + oj, acc[c][oj]);
    }
}

// ---------------- fallback (ws too small): naive but correct ----------------
__global__ __launch_bounds__(256) void reblur_naive(const float* __restrict__ img,
                                                    const float* __restrict__ Kern,
                                                    float* __restrict__ out) {
    const int lane = threadIdx.x & 63;
    const int dy   = threadIdx.x >> 6;
    const int c    = blockIdx.x >> 8;
    const int bb   = blockIdx.x & 255;
    const int h    = bb >> 1;
    const int wt   = bb & 1;
    const int wb   = wt * 64 + lane;
    const int y    = 4 * h + dy;

    float acc[4] = {0.f, 0.f, 0.f, 0.f};
    const float* kb = Kern + h * NB + wb;
#pragma unroll 1
    for (int u = 0; u < 33; ++u) {
        const int iy = min(max(y + u - 16, 0), HH - 1);
        float row[36];
#pragma unroll
        for (int e = 0; e < 36; ++e) {
            const int ix = min(max(4 * wb + e - 16, 0), WW - 1);
            row[e]       = img[(c * HH + iy) * WW + ix];
        }
#pragma unroll
        for (int v = 0; v < 33; ++v) {
            const float w = kb[(u * 33 + v) * KSTR];
#pragma unroll
            for (int oj = 0; oj < 4; ++oj)
                acc[oj] = fmaf(row[v + oj], w, acc[oj]);
        }
    }
    float4 o;
    o.x = acc[0]; o.y = acc[1]; o.z = acc[2]; o.w = acc[3];
    *reinterpret_cast<float4*>(out + (size_t)(c * HH + y) * WW + 4 * wb) = o;
}

extern "C" void kernel_launch(void* const* d_in, const int* in_sizes, int n_in,
                              void* d_out, int out_size, void* d_ws, size_t ws_size,
                              hipStream_t stream) {
    const float* img  = (const float*)d_in[0];
    const float* Kern = (const float*)d_in[1];
    float* out        = (float*)d_out;

    if (ws_size >= (size_t)PADN * sizeof(float)) {
        float* gpad = (float*)d_ws;
        pad_f32<<<(PADN + 255) / 256, 256, 0, stream>>>(img, gpad, out);
        reblur_f32<<<1024, 256, 0, stream>>>(gpad, Kern, out);
    } else if (ws_size >= (size_t)PADN * sizeof(unsigned short)) {
        unsigned short* gpad = (unsigned short*)d_ws;
        pad_bf16<<<(PADN + 255) / 256, 256, 0, stream>>>(img, gpad, out);
        reblur_bf16<<<1024, 256, 0, stream>>>(gpad, Kern, out);
    } else {
        reblur_naive<<<768, 256, 0, stream>>>(img, Kern, out);
    }
}